// Round 14
// baseline (112.036 us; speedup 1.0000x reference)
//
#include <hip/hip_runtime.h>
#include <stdint.h>

// LIF scan, chunk-parallel with warm-up convergence.
// v' = fma(v, 0.95, I); s = sigmoid(10(v'-1)); hard = v'>1; v'' = v'*(1-s)
// Outputs (f32, concat): spikes[B*L], hard_latency[B], soft_latency[B]
//
// R14: single-variable ablation of R13 — NT stores -> plain cached stores.
//      NT bypasses L2 write-aggregation (2048 concurrent 256B streams at
//      16KB stride = DRAM write page-thrash); and NT's justification was
//      void (R4 plain stores: FETCH 96.4MB = identical I L3-residency).
//      Everything else identical to R13: 4 independent waves/block, 16KB
//      in-place LDS per wave, 2 blocks/CU = 8 waves/CU, reg-bounce drain,
//      exact vmcnt(16/0), 512 blocks all-resident single round.

constexpr float TH_   = 1.0f;
constexpr float LEAK  = 0.95f;                   // 1 - 1/tau
constexpr float KL2E  = 14.426950408889634f;     // K * log2(e)
constexpr int   LDIM   = 4096;
constexpr int   TILE_T = 64;                     // timesteps per tile
constexpr int   CH     = TILE_T / 4;             // 16 float4 chunks per row
constexpr int   NCHUNK = 16;                     // time-parallel chunks
constexpr int   WARM   = 128;                    // warm-up steps

typedef __attribute__((address_space(1))) const unsigned int glob_u32;
typedef __attribute__((address_space(3))) unsigned int lds_u32;

__device__ __forceinline__ float exp2_fast(float x) {
#if __has_builtin(__builtin_amdgcn_exp2f)
  return __builtin_amdgcn_exp2f(x);
#else
  return exp2f(x);
#endif
}

template <bool LAT>
__device__ __forceinline__ float lif_step(float& v, float Iv, float tf, float& latf) {
  v = fmaf(v, LEAK, Iv);                       // Euler, fused
  float e = exp2_fast(fmaf(-KL2E, v, KL2E));   // exp(-K*(v-TH)) in exp2 domain
  float s = __builtin_amdgcn_rcpf(1.0f + e);   // sigmoid
  if (LAT) {
    if (v > TH_) latf = fminf(latf, tf);       // first hard crossing (pre-reset v)
  }
  v = fmaf(-s, v, v);                          // v *= (1 - s)
  return s;
}

// ---- 64 rows x 64 cols tile, float4-chunk XOR swizzle (R4-proven) ----
// LDS: float4 buf[64*16]; linear slot (r*16+p) holds logical chunk p^(r&15).
// global_load_lds dest is lane-linear; per-lane GLOBAL src is pre-swizzled.

__device__ __forceinline__ void stage_tile(const float* __restrict__ I, float4* buf,
                                           int rowbase, int t0, int lane) {
  const int sub = lane >> 4;                   // 0..3
  const int p   = lane & 15;
#pragma unroll
  for (int i = 0; i < CH; ++i) {
    const int r = 4 * i + sub;
    const int c = p ^ (r & 15);
    const float* src = I + (size_t)(rowbase + r) * LDIM + t0 + 4 * c;
    __builtin_amdgcn_global_load_lds((glob_u32*)src, (lds_u32*)(buf + i * 64),
                                     16, 0, 0);   // 64 lanes x 16B -> 1KB slab
  }
}

// Reg-bounce drain, part 1: swizzled ds_read_b128 of the S tile into regs.
__device__ __forceinline__ void read_tile_regs(const float4* buf, float4* d,
                                               int lane) {
  const int c     = lane & 15;
  const int rbase = lane >> 4;
#pragma unroll
  for (int i = 0; i < CH; ++i) {
    const int r = 4 * i + rbase;
    d[i] = buf[r * CH + (c ^ (r & 15))];       // conflict-free (2-way, free)
  }
}

// Reg-bounce drain, part 2: 16 cached stores, 256B contiguous per row-quad.
__device__ __forceinline__ void store_tile_regs(const float4* d,
                                                float* __restrict__ gOut, int lane) {
  const int c     = lane & 15;
  const int rbase = lane >> 4;
#pragma unroll
  for (int i = 0; i < CH; ++i) {
    const int r = 4 * i + rbase;
    *reinterpret_cast<float4*>(gOut + (size_t)r * LDIM + 4 * c) = d[i];  // plain store
  }
}

// In-place: reads I chunk j+1 (prefetch), overwrites chunk j with S.
template <bool LAT>
__device__ __forceinline__ void process_tile(float4* __restrict__ buf, int lane,
                                             float& v, float& latf,
                                             float& ss, float& sst, float& tf) {
  const int m    = lane & 15;
  const int base = lane * CH;
  float4 c = buf[base + (0 ^ m)];
#pragma unroll
  for (int j = 0; j < CH; ++j) {
    float4 Ij = c;
    if (j + 1 < CH) c = buf[base + ((j + 1) ^ m)];
    float4 S;
    S.x = lif_step<LAT>(v, Ij.x, tf + 0.0f, latf);
    S.y = lif_step<LAT>(v, Ij.y, tf + 1.0f, latf);
    S.z = lif_step<LAT>(v, Ij.z, tf + 2.0f, latf);
    S.w = lif_step<LAT>(v, Ij.w, tf + 3.0f, latf);
    float g = (S.x + S.y) + (S.z + S.w);
    ss += g;
    sst = fmaf(g, tf, sst);
    sst += S.y;
    sst = fmaf(2.0f, S.z, sst);
    sst = fmaf(3.0f, S.w, sst);
    tf += 4.0f;
    buf[base + (j ^ m)] = S;                   // in-place S write
  }
}

__device__ __forceinline__ void warm_tile(const float4* __restrict__ buf, int lane,
                                          float& v) {
  const int m    = lane & 15;
  const int base = lane * CH;
  float dummy = 0.0f;
  float4 c = buf[base + (0 ^ m)];
#pragma unroll
  for (int j = 0; j < CH; ++j) {
    float4 Ij = c;
    if (j + 1 < CH) c = buf[base + ((j + 1) ^ m)];
    lif_step<false>(v, Ij.x, 0.0f, dummy);
    lif_step<false>(v, Ij.y, 0.0f, dummy);
    lif_step<false>(v, Ij.z, 0.0f, dummy);
    lif_step<false>(v, Ij.w, 0.0f, dummy);
  }
}

// Per-wave schedule; 4 independent waves per block (LDS-allocation trick).
template <bool DIRECT>
__global__ void __launch_bounds__(256) lif_scan(
    const float* __restrict__ I, float* __restrict__ spikes,
    float* __restrict__ pA, float* __restrict__ pB, float* __restrict__ pL,
    int B, int own, int warm) {
  __shared__ float4 lds[4][64 * CH];   // one 16 KiB in-place region per wave

  const int tid   = threadIdx.x;
  const int lane  = tid & 63;
  const int wid   = tid >> 6;          // 0..3
  const int row0  = blockIdx.x * 256 + wid * 64;
  const int row   = row0 + lane;
  const int chunk = blockIdx.y;
  float4*   buf   = lds[wid];

  const int t_own = chunk * own;
  const int t_beg = (chunk == 0) ? 0 : t_own - warm;
  const int nwarm = (t_own - t_beg) / TILE_T;
  const int ntile = nwarm + own / TILE_T;

  float v = 0.0f;
  float latf = (float)LDIM;
  float ss = 0.0f, sst = 0.0f, tf = (float)t_own;

  stage_tile(I, buf, row0, t_beg, lane);

  for (int k = 0; k < ntile; ++k) {
    const int  t0       = t_beg + k * TILE_T;
    const bool is_warm  = (k < nwarm);
    const bool prev_own = (k > 0) && (k - 1 >= nwarm);
    const bool has_next = (k + 1 < ntile);

    // wait: target = stage(k)'s 16 loads (issued end of iter k-1 / prologue).
    // newer = stores(k-1) [16 if prev_own] — issued AFTER stage(k), so
    // vmcnt(16) skips them; they retire with a full iteration of slack.
    if (prev_own) asm volatile("s_waitcnt vmcnt(16)" ::: "memory");
    else          asm volatile("s_waitcnt vmcnt(0)"  ::: "memory");

    if (is_warm) {
      warm_tile(buf, lane, v);
      __builtin_amdgcn_sched_barrier(0);               // reads precede refill
      if (has_next) stage_tile(I, buf, row0, t0 + TILE_T, lane);
    } else {
      if (!__all(latf < (float)LDIM))
        process_tile<true >(buf, lane, v, latf, ss, sst, tf);
      else
        process_tile<false>(buf, lane, v, latf, ss, sst, tf);
      float4 d[CH];
      read_tile_regs(buf, d, lane);                    // S tile -> regs
      asm volatile("s_waitcnt lgkmcnt(0)" ::: "memory");
      __builtin_amdgcn_sched_barrier(0);               // reads done before refill
      if (has_next) stage_tile(I, buf, row0, t0 + TILE_T, lane);
      __builtin_amdgcn_sched_barrier(0);               // loads issued before stores
      store_tile_regs(d, spikes + (size_t)row0 * LDIM + t0, lane);  // 16 stores
    }
  }

  if (DIRECT) {
    pL[row] = latf;
    pA[row] = sst / (ss + 1e-6f);
  } else {
    const size_t o = (size_t)chunk * B + row;
    pA[o] = ss;
    pB[o] = sst;
    pL[o] = latf;
  }
}

extern "C" __global__ void __launch_bounds__(256) lif_reduce(
    const float* __restrict__ pA, const float* __restrict__ pB,
    const float* __restrict__ pL, float* __restrict__ hard,
    float* __restrict__ soft, int B) {
  const int r = blockIdx.x * 256 + threadIdx.x;
  if (r >= B) return;
  float a = 0.0f, b = 0.0f, l = (float)LDIM;
  for (int c = 0; c < NCHUNK; ++c) {
    a += pA[(size_t)c * B + r];
    b += pB[(size_t)c * B + r];
    l = fminf(l, pL[(size_t)c * B + r]);
  }
  hard[r] = l;
  soft[r] = b / (a + 1e-6f);
}

extern "C" void kernel_launch(void* const* d_in, const int* in_sizes, int n_in,
                              void* d_out, int out_size, void* d_ws, size_t ws_size,
                              hipStream_t stream) {
  const float* I = (const float*)d_in[0];
  const int B = in_sizes[0] / LDIM;            // 8192
  float* out    = (float*)d_out;
  float* spikes = out;
  float* hard   = out + (size_t)B * LDIM;
  float* soft   = hard + B;

  const size_t need = (size_t)3 * NCHUNK * B * sizeof(float);
  if (ws_size >= need) {
    float* pA = (float*)d_ws;
    float* pB = pA + (size_t)NCHUNK * B;
    float* pL = pB + (size_t)NCHUNK * B;
    hipLaunchKernelGGL((lif_scan<false>), dim3(B / 256, NCHUNK), dim3(256), 0, stream,
                       I, spikes, pA, pB, pL, B, LDIM / NCHUNK, WARM);
    hipLaunchKernelGGL(lif_reduce, dim3((B + 255) / 256), dim3(256), 0, stream,
                       pA, pB, pL, hard, soft, B);
  } else {
    // fallback: single chunk, direct outputs (hard<-pL, soft<-pA)
    hipLaunchKernelGGL((lif_scan<true>), dim3(B / 256, 1), dim3(256), 0, stream,
                       I, spikes, soft, soft, hard, B, LDIM, 0);
  }
}

// Round 15
// 50.557 us; speedup vs baseline: 2.2160x; 2.2160x over previous
//
#include <hip/hip_runtime.h>
#include <stdint.h>

// LIF scan, chunk-parallel with warm-up convergence.
// v' = fma(v, 0.95, I); s = sigmoid(10(v'-1)); hard = v'>1; v'' = v'*(1-s)
// Outputs (f32, concat): spikes[B*L], hard_latency[B], soft_latency[B]
//
// R15: R13 (best, 56.2us) with WARM 128->64. R14 proved NT stores essential
//      (plain stores: 2x write amplification via write-allocate + I evicted
//      from L3 -> 112us). R13's residual inefficiency is the warm-up head:
//      2 warm tiles/chunk = 33% of iterations issue no stores while the
//      write path otherwise saturates (~3.5 TB/s during own phase). WARM=64
//      halves that head. Seam error: leak damping 0.95^64=0.037, and any
//      spike in the window contracts by (1-s)~0; margin was 8 vs 49.6.

constexpr float TH_   = 1.0f;
constexpr float LEAK  = 0.95f;                   // 1 - 1/tau
constexpr float KL2E  = 14.426950408889634f;     // K * log2(e)
constexpr int   LDIM   = 4096;
constexpr int   TILE_T = 64;                     // timesteps per tile
constexpr int   CH     = TILE_T / 4;             // 16 float4 chunks per row
constexpr int   NCHUNK = 16;                     // time-parallel chunks
constexpr int   WARM   = 64;                     // warm-up steps (= 1 tile)

typedef __attribute__((address_space(1))) const unsigned int glob_u32;
typedef __attribute__((address_space(3))) unsigned int lds_u32;
typedef float __attribute__((ext_vector_type(4))) f32x4;   // NT-store-compatible

__device__ __forceinline__ float exp2_fast(float x) {
#if __has_builtin(__builtin_amdgcn_exp2f)
  return __builtin_amdgcn_exp2f(x);
#else
  return exp2f(x);
#endif
}

template <bool LAT>
__device__ __forceinline__ float lif_step(float& v, float Iv, float tf, float& latf) {
  v = fmaf(v, LEAK, Iv);                       // Euler, fused
  float e = exp2_fast(fmaf(-KL2E, v, KL2E));   // exp(-K*(v-TH)) in exp2 domain
  float s = __builtin_amdgcn_rcpf(1.0f + e);   // sigmoid
  if (LAT) {
    if (v > TH_) latf = fminf(latf, tf);       // first hard crossing (pre-reset v)
  }
  v = fmaf(-s, v, v);                          // v *= (1 - s)
  return s;
}

// ---- 64 rows x 64 cols tile, float4-chunk XOR swizzle (R4-proven) ----
// LDS: float4 buf[64*16]; linear slot (r*16+p) holds logical chunk p^(r&15).
// global_load_lds dest is lane-linear; per-lane GLOBAL src is pre-swizzled.

__device__ __forceinline__ void stage_tile(const float* __restrict__ I, float4* buf,
                                           int rowbase, int t0, int lane) {
  const int sub = lane >> 4;                   // 0..3
  const int p   = lane & 15;
#pragma unroll
  for (int i = 0; i < CH; ++i) {
    const int r = 4 * i + sub;
    const int c = p ^ (r & 15);
    const float* src = I + (size_t)(rowbase + r) * LDIM + t0 + 4 * c;
    __builtin_amdgcn_global_load_lds((glob_u32*)src, (lds_u32*)(buf + i * 64),
                                     16, 0, 0);   // 64 lanes x 16B -> 1KB slab
  }
}

// Reg-bounce drain, part 1: swizzled ds_read_b128 of the S tile into regs.
__device__ __forceinline__ void read_tile_regs(const float4* buf, float4* d,
                                               int lane) {
  const int c     = lane & 15;
  const int rbase = lane >> 4;
#pragma unroll
  for (int i = 0; i < CH; ++i) {
    const int r = 4 * i + rbase;
    d[i] = buf[r * CH + (c ^ (r & 15))];       // conflict-free (2-way, free)
  }
}

// Reg-bounce drain, part 2: 16 NT stores, 256B contiguous per row-quad.
__device__ __forceinline__ void store_tile_regs(const float4* d,
                                                float* __restrict__ gOut, int lane) {
  const int c     = lane & 15;
  const int rbase = lane >> 4;
#pragma unroll
  for (int i = 0; i < CH; ++i) {
    const int r = 4 * i + rbase;
    f32x4 w = {d[i].x, d[i].y, d[i].z, d[i].w};
    __builtin_nontemporal_store(w,
        reinterpret_cast<f32x4*>(gOut + (size_t)r * LDIM + 4 * c));
  }
}

// In-place: reads I chunk j+1 (prefetch), overwrites chunk j with S.
template <bool LAT>
__device__ __forceinline__ void process_tile(float4* __restrict__ buf, int lane,
                                             float& v, float& latf,
                                             float& ss, float& sst, float& tf) {
  const int m    = lane & 15;
  const int base = lane * CH;
  float4 c = buf[base + (0 ^ m)];
#pragma unroll
  for (int j = 0; j < CH; ++j) {
    float4 Ij = c;
    if (j + 1 < CH) c = buf[base + ((j + 1) ^ m)];
    float4 S;
    S.x = lif_step<LAT>(v, Ij.x, tf + 0.0f, latf);
    S.y = lif_step<LAT>(v, Ij.y, tf + 1.0f, latf);
    S.z = lif_step<LAT>(v, Ij.z, tf + 2.0f, latf);
    S.w = lif_step<LAT>(v, Ij.w, tf + 3.0f, latf);
    float g = (S.x + S.y) + (S.z + S.w);
    ss += g;
    sst = fmaf(g, tf, sst);
    sst += S.y;
    sst = fmaf(2.0f, S.z, sst);
    sst = fmaf(3.0f, S.w, sst);
    tf += 4.0f;
    buf[base + (j ^ m)] = S;                   // in-place S write
  }
}

__device__ __forceinline__ void warm_tile(const float4* __restrict__ buf, int lane,
                                          float& v) {
  const int m    = lane & 15;
  const int base = lane * CH;
  float dummy = 0.0f;
  float4 c = buf[base + (0 ^ m)];
#pragma unroll
  for (int j = 0; j < CH; ++j) {
    float4 Ij = c;
    if (j + 1 < CH) c = buf[base + ((j + 1) ^ m)];
    lif_step<false>(v, Ij.x, 0.0f, dummy);
    lif_step<false>(v, Ij.y, 0.0f, dummy);
    lif_step<false>(v, Ij.z, 0.0f, dummy);
    lif_step<false>(v, Ij.w, 0.0f, dummy);
  }
}

// Per-wave schedule; 4 independent waves per block (LDS-allocation trick).
template <bool DIRECT>
__global__ void __launch_bounds__(256) lif_scan(
    const float* __restrict__ I, float* __restrict__ spikes,
    float* __restrict__ pA, float* __restrict__ pB, float* __restrict__ pL,
    int B, int own, int warm) {
  __shared__ float4 lds[4][64 * CH];   // one 16 KiB in-place region per wave

  const int tid   = threadIdx.x;
  const int lane  = tid & 63;
  const int wid   = tid >> 6;          // 0..3
  const int row0  = blockIdx.x * 256 + wid * 64;
  const int row   = row0 + lane;
  const int chunk = blockIdx.y;
  float4*   buf   = lds[wid];

  const int t_own = chunk * own;
  const int t_beg = (chunk == 0) ? 0 : t_own - warm;
  const int nwarm = (t_own - t_beg) / TILE_T;
  const int ntile = nwarm + own / TILE_T;

  float v = 0.0f;
  float latf = (float)LDIM;
  float ss = 0.0f, sst = 0.0f, tf = (float)t_own;

  stage_tile(I, buf, row0, t_beg, lane);

  for (int k = 0; k < ntile; ++k) {
    const int  t0       = t_beg + k * TILE_T;
    const bool is_warm  = (k < nwarm);
    const bool prev_own = (k > 0) && (k - 1 >= nwarm);
    const bool has_next = (k + 1 < ntile);

    // wait: target = stage(k)'s 16 loads (issued end of iter k-1 / prologue).
    // newer = stores(k-1) [16 if prev_own] — issued AFTER stage(k), so
    // vmcnt(16) skips them; they retire with a full iteration of slack.
    if (prev_own) asm volatile("s_waitcnt vmcnt(16)" ::: "memory");
    else          asm volatile("s_waitcnt vmcnt(0)"  ::: "memory");

    if (is_warm) {
      warm_tile(buf, lane, v);
      __builtin_amdgcn_sched_barrier(0);               // reads precede refill
      if (has_next) stage_tile(I, buf, row0, t0 + TILE_T, lane);
    } else {
      if (!__all(latf < (float)LDIM))
        process_tile<true >(buf, lane, v, latf, ss, sst, tf);
      else
        process_tile<false>(buf, lane, v, latf, ss, sst, tf);
      float4 d[CH];
      read_tile_regs(buf, d, lane);                    // S tile -> regs
      asm volatile("s_waitcnt lgkmcnt(0)" ::: "memory");
      __builtin_amdgcn_sched_barrier(0);               // reads done before refill
      if (has_next) stage_tile(I, buf, row0, t0 + TILE_T, lane);
      __builtin_amdgcn_sched_barrier(0);               // loads issued before stores
      store_tile_regs(d, spikes + (size_t)row0 * LDIM + t0, lane);  // 16 NT st
    }
  }

  if (DIRECT) {
    pL[row] = latf;
    pA[row] = sst / (ss + 1e-6f);
  } else {
    const size_t o = (size_t)chunk * B + row;
    pA[o] = ss;
    pB[o] = sst;
    pL[o] = latf;
  }
}

extern "C" __global__ void __launch_bounds__(256) lif_reduce(
    const float* __restrict__ pA, const float* __restrict__ pB,
    const float* __restrict__ pL, float* __restrict__ hard,
    float* __restrict__ soft, int B) {
  const int r = blockIdx.x * 256 + threadIdx.x;
  if (r >= B) return;
  float a = 0.0f, b = 0.0f, l = (float)LDIM;
  for (int c = 0; c < NCHUNK; ++c) {
    a += pA[(size_t)c * B + r];
    b += pB[(size_t)c * B + r];
    l = fminf(l, pL[(size_t)c * B + r]);
  }
  hard[r] = l;
  soft[r] = b / (a + 1e-6f);
}

extern "C" void kernel_launch(void* const* d_in, const int* in_sizes, int n_in,
                              void* d_out, int out_size, void* d_ws, size_t ws_size,
                              hipStream_t stream) {
  const float* I = (const float*)d_in[0];
  const int B = in_sizes[0] / LDIM;            // 8192
  float* out    = (float*)d_out;
  float* spikes = out;
  float* hard   = out + (size_t)B * LDIM;
  float* soft   = hard + B;

  const size_t need = (size_t)3 * NCHUNK * B * sizeof(float);
  if (ws_size >= need) {
    float* pA = (float*)d_ws;
    float* pB = pA + (size_t)NCHUNK * B;
    float* pL = pB + (size_t)NCHUNK * B;
    hipLaunchKernelGGL((lif_scan<false>), dim3(B / 256, NCHUNK), dim3(256), 0, stream,
                       I, spikes, pA, pB, pL, B, LDIM / NCHUNK, WARM);
    hipLaunchKernelGGL(lif_reduce, dim3((B + 255) / 256), dim3(256), 0, stream,
                       pA, pB, pL, hard, soft, B);
  } else {
    // fallback: single chunk, direct outputs (hard<-pL, soft<-pA)
    hipLaunchKernelGGL((lif_scan<true>), dim3(B / 256, 1), dim3(256), 0, stream,
                       I, spikes, soft, soft, hard, B, LDIM, 0);
  }
}